// Round 7
// baseline (827.847 us; speedup 1.0000x reference)
//
#include <hip/hip_runtime.h>
#include <hip/hip_bf16.h>
#include <math.h>

#define DMODEL 512
#define SEQ    257
#define BATCH  64
#define ROWS   (BATCH * SEQ)   // 16448
#define ROWSP  16512
#define HCHUNK 8224            // ROWS/2, per-chunk rows for KAN

typedef unsigned short ushortT;
typedef __attribute__((ext_vector_type(8))) __bf16 bf16x8;
typedef __attribute__((ext_vector_type(4))) float f32x4;

__device__ __forceinline__ ushortT f2bf(float v) {
    __hip_bfloat16 t = __float2bfloat16(v);
    return *(ushortT*)&t;
}
__device__ __forceinline__ float bf2f(ushortT u) {
    return __bfloat162float(*(__hip_bfloat16*)&u);
}

// async 16B global->LDS (wave-uniform LDS base + lane*16)
__device__ __forceinline__ void gl16(const ushortT* g, ushortT* l) {
    __builtin_amdgcn_global_load_lds(
        (const __attribute__((address_space(1))) void*)g,
        (__attribute__((address_space(3))) void*)l, 16, 0, 0);
}

// ---------------- cubic B-spline bases (closed form, uniform grid) -------------
__device__ __forceinline__ void bspline8(float x, float bas[8]) {
    const float k6 = 1.0f / 6.0f;
    float t = (x + 2.2f) * 2.5f;
    float fm = floorf(t);
    int m = (int)fm;
    float u = t - fm;
    float u2 = u * u, u3 = u2 * u;
    float omu = 1.0f - u;
    float p0 = u3 * k6;
    float p1 = (-3.0f * u3 + 3.0f * u2 + 3.0f * u + 1.0f) * k6;
    float p2 = (3.0f * u3 - 6.0f * u2 + 4.0f) * k6;
    float p3 = omu * omu * omu * k6;
#pragma unroll
    for (int q = 0; q < 8; ++q) {
        int d = m - q;
        float v = (d == 0) ? p0 : (d == 1) ? p1 : (d == 2) ? p2 : (d == 3) ? p3 : 0.0f;
        bas[q] = v;
    }
}

// ---------------- bf16 MFMA GEMM (global_load_lds staging, split-K capable) ----
// C[M,N] = A[M,K] @ B[N,K]^T. Tiles 128x128, 4 waves. blockIdx.z = K-split slice.
// MODE 0: f32 store + bias (+R residual). MODE 1: bf16 store + bias.
// MODE 3: f32 atomicAdd, no bias (KAN1 partials). MODE 4: atomicAdd into out with
//         (b,p-1) remap, p==0 dropped, no bias (KAN2).
template<int MODE>
__global__ __launch_bounds__(256) void gemm_t(
    const ushortT* __restrict__ A, const ushortT* __restrict__ B,
    const float* __restrict__ bias, const float* __restrict__ R,
    void* __restrict__ Cv, int N, int K, int Mreal, int rowoff, int Ks) {
    __shared__ __align__(16) ushortT As[128 * 32];
    __shared__ __align__(16) ushortT Bs[128 * 32];
    const int tid = threadIdx.x;
    const int wave = tid >> 6, lane = tid & 63;
    // bijective XCD swizzle (8 XCDs) over the (x,y) plane
    const int nwg = gridDim.x * gridDim.y;
    const int lin = blockIdx.y * gridDim.x + blockIdx.x;
    const int xcd = lin & 7, sidx = lin >> 3;
    const int qn = nwg >> 3, rn = nwg & 7;
    const int nlin = (xcd < rn ? xcd * (qn + 1) : rn * (qn + 1) + (xcd - rn) * qn) + sidx;
    const int bm = (nlin / gridDim.x) * 128, bn = (nlin % gridDim.x) * 128;
    const int wm = (wave >> 1) * 64, wn = (wave & 1) * 64;
    const int srow = tid >> 2;
    const int scol = (tid & 3) * 8;
    const int mrow = lane & 15;
    const int kq = (lane >> 4) * 8;
    f32x4 acc[4][4];
#pragma unroll
    for (int i = 0; i < 4; ++i)
#pragma unroll
        for (int j = 0; j < 4; ++j) acc[i][j] = (f32x4){0.f, 0.f, 0.f, 0.f};

    // row-clamped A staging (allows Mreal not multiple of 128)
    int ar0 = bm + srow;      if (ar0 > Mreal - 1) ar0 = Mreal - 1;
    int ar1 = bm + srow + 64; if (ar1 > Mreal - 1) ar1 = Mreal - 1;
    const ushortT* Ab0 = A + (size_t)ar0 * K + scol;
    const ushortT* Ab1 = A + (size_t)ar1 * K + scol;
    const ushortT* Bb  = B + (size_t)(bn + srow) * K + scol;
    ushortT* AsW = As + wave * 512;
    ushortT* BsW = Bs + wave * 512;
    const int kb = blockIdx.z * Ks;
    const int ke = kb + Ks;
    for (int k0 = kb; k0 < ke; k0 += 32) {
        __syncthreads();
        gl16(Ab0 + k0, AsW);
        gl16(Ab1 + k0, AsW + 2048);
        gl16(Bb + k0, BsW);
        gl16(Bb + k0 + (size_t)64 * K, BsW + 2048);
        __syncthreads();
        bf16x8 af[4], bf[4];
#pragma unroll
        for (int i = 0; i < 4; ++i) af[i] = *(const bf16x8*)&As[(wm + i * 16 + mrow) * 32 + kq];
#pragma unroll
        for (int j = 0; j < 4; ++j) bf[j] = *(const bf16x8*)&Bs[(wn + j * 16 + mrow) * 32 + kq];
#pragma unroll
        for (int i = 0; i < 4; ++i)
#pragma unroll
            for (int j = 0; j < 4; ++j)
                acc[i][j] = __builtin_amdgcn_mfma_f32_16x16x32_bf16(af[i], bf[j], acc[i][j], 0, 0, 0);
    }
    const int r0q = (lane >> 4) * 4;
    const int cn = lane & 15;
#pragma unroll
    for (int i = 0; i < 4; ++i) {
#pragma unroll
        for (int j = 0; j < 4; ++j) {
            int col = bn + wn + j * 16 + cn;
            float bv = (MODE <= 1) ? bias[col] : 0.0f;
#pragma unroll
            for (int r = 0; r < 4; ++r) {
                int row = bm + wm + i * 16 + r0q + r;
                float v = acc[i][j][r] + bv;
                if (MODE == 1) {
                    if (row < Mreal)
                        ((__hip_bfloat16*)Cv)[(size_t)row * N + col] = __float2bfloat16(v);
                } else if (MODE == 0) {
                    if (row < Mreal) {
                        size_t idx = (size_t)row * N + col;
                        if (R) v += R[idx];
                        ((float*)Cv)[idx] = v;
                    }
                } else if (MODE == 3) {
                    if (row < Mreal)
                        atomicAdd(&((float*)Cv)[(size_t)row * N + col], v);
                } else {  // MODE 4
                    if (row < Mreal) {
                        int grow = rowoff + row;
                        int bb = grow / SEQ;
                        int pp = grow - bb * SEQ;
                        if (pp > 0)
                            atomicAdd(&((float*)Cv)[((size_t)(bb * 256 + pp - 1)) * 256 + col], v);
                    }
                }
            }
        }
    }
}

// ---------------- attention v3: 4 waves / 64 q-rows, padded LDS strides --------
// grid (5 qtiles, 512 bh); block 256 (4 waves). LDS 80128 B -> 2 blocks/CU.
// K view [272][72] (stride 144B, 2-way); Vt [64][328]+XOR (2-way); Sc stride 296.
__global__ __launch_bounds__(256) void attn_mf2(const ushortT* __restrict__ qkvb,
                                                __hip_bfloat16* __restrict__ o) {
    __shared__ __align__(16) ushortT KV[20992];  // max(272*72, 64*328)
    __shared__ __align__(16) ushortT Sc[64 * 296];
    __shared__ float Linv[64];
    const int tid = threadIdx.x;
    const int wave = tid >> 6, lane = tid & 63;
    const int l15 = lane & 15;
    const int quad = lane >> 4;
    // XCD-chunked swizzle: nwg = 2560 (div by 8); 5 qtiles of one bh share an XCD L2
    const int lin = blockIdx.y * gridDim.x + blockIdx.x;
    const int w = (lin & 7) * 320 + (lin >> 3);
    const int q0 = (w % 5) * 64;
    const int bh = w / 5;
    const int h = bh & 7, b = bh >> 3;
    const size_t base = (size_t)(b * SEQ) * 1536;

    // stage K [272][72] (rows >= SEQ zero)
    for (int g = tid; g < 272 * 8; g += 256) {
        int k = g >> 3;
        int d0 = (g & 7) * 8;
        int4 v;
        if (k < SEQ) v = *(const int4*)&qkvb[base + (size_t)k * 1536 + 512 + h * 64 + d0];
        else v = (int4){0, 0, 0, 0};
        *(int4*)&KV[k * 72 + d0] = v;
    }
    // Q fragments, exact *0.125 (power of 2)
    int q = q0 + wave * 16 + l15;
    if (q > SEQ - 1) q = SEQ - 1;
    bf16x8 qf[2];
#pragma unroll
    for (int c = 0; c < 2; ++c) {
        union { bf16x8 v8; ushortT u[8]; } r;
        r.v8 = *(const bf16x8*)&qkvb[base + (size_t)q * 1536 + h * 64 + quad * 8 + c * 32];
#pragma unroll
        for (int i = 0; i < 8; ++i)
            r.u[i] = f2bf(bf2f(r.u[i]) * 0.125f);
        qf[c] = r.v8;
    }
    __syncthreads();

    // S = (Q/8) K^T -> Sc bf16 (cols 0..271)
    __builtin_amdgcn_s_setprio(1);
    for (int kt = 0; kt < 17; ++kt) {
        f32x4 sacc = (f32x4){0.f, 0.f, 0.f, 0.f};
#pragma unroll
        for (int c = 0; c < 2; ++c) {
            bf16x8 kf = *(const bf16x8*)&KV[(kt * 16 + l15) * 72 + c * 32 + quad * 8];
            sacc = __builtin_amdgcn_mfma_f32_16x16x32_bf16(qf[c], kf, sacc, 0, 0, 0);
        }
#pragma unroll
        for (int r = 0; r < 4; ++r)
            Sc[(wave * 16 + quad * 4 + r) * 296 + kt * 16 + l15] = f2bf(sacc[r]);
    }
    __builtin_amdgcn_s_setprio(0);
    __syncthreads();   // all S reads of K done; Sc fully written

    // stage Vt [64][328] with XOR swizzle: addr(d,key) = d*328 + (key ^ ((d>>3)*8))
    for (int g = tid; g < 288 * 8; g += 256) {
        int key = g >> 3;
        int d0 = (g & 7) * 8;           // swizzle mask for d in [d0,d0+8)
        ushortT tmp[8];
        if (key < SEQ) {
            int4 v = *(const int4*)&qkvb[base + (size_t)key * 1536 + 1024 + h * 64 + d0];
            *(int4*)tmp = v;
        } else {
#pragma unroll
            for (int i = 0; i < 8; ++i) tmp[i] = 0;
        }
        int sk = key ^ d0;
#pragma unroll
        for (int i = 0; i < 8; ++i) KV[(d0 + i) * 328 + sk] = tmp[i];
    }
    // softmax: 4 threads/row, vectorized bf16x8; pad cols [SEQ,288) = -1e30 first
    {
        int row = tid >> 2;             // 0..63
        int stripe = tid & 3;
        ushortT* sr = &Sc[row * 296];
        ushortT NEG = f2bf(-1e30f);
        for (int c = SEQ + stripe; c < 288; c += 4) sr[c] = NEG;
        float m = -1e30f;
#pragma unroll
        for (int it = 0; it < 9; ++it) {
            union { bf16x8 v8; ushortT u[8]; } rr;
            rr.v8 = *(const bf16x8*)&sr[stripe * 8 + it * 32];
#pragma unroll
            for (int j = 0; j < 8; ++j) m = fmaxf(m, bf2f(rr.u[j]));
        }
        m = fmaxf(m, __shfl_xor(m, 1, 64));
        m = fmaxf(m, __shfl_xor(m, 2, 64));
        float l = 0.f;
#pragma unroll
        for (int it = 0; it < 9; ++it) {
            union { bf16x8 v8; ushortT u[8]; } rr;
            ushortT* p = &sr[stripe * 8 + it * 32];
            rr.v8 = *(const bf16x8*)p;
#pragma unroll
            for (int j = 0; j < 8; ++j) {
                float e = __expf(bf2f(rr.u[j]) - m);
                l += e;
                rr.u[j] = f2bf(e);
            }
            *(bf16x8*)p = rr.v8;
        }
        l += __shfl_xor(l, 1, 64);
        l += __shfl_xor(l, 2, 64);
        if (stripe == 0) Linv[row] = 1.0f / l;
    }
    __syncthreads();

    // O = P V
    f32x4 oacc[4];
#pragma unroll
    for (int nf = 0; nf < 4; ++nf) oacc[nf] = (f32x4){0.f, 0.f, 0.f, 0.f};
    __builtin_amdgcn_s_setprio(1);
    for (int kc = 0; kc < 9; ++kc) {
        bf16x8 pf = *(const bf16x8*)&Sc[(wave * 16 + l15) * 296 + kc * 32 + quad * 8];
#pragma unroll
        for (int nf = 0; nf < 4; ++nf) {
            int d = nf * 16 + l15;
            int mask = ((d >> 3) & 7) * 8;
            bf16x8 vf = *(const bf16x8*)&KV[d * 328 + ((kc * 32 + quad * 8) ^ mask)];
            oacc[nf] = __builtin_amdgcn_mfma_f32_16x16x32_bf16(pf, vf, oacc[nf], 0, 0, 0);
        }
    }
    __builtin_amdgcn_s_setprio(0);
#pragma unroll
    for (int nf = 0; nf < 4; ++nf) {
#pragma unroll
        for (int r = 0; r < 4; ++r) {
            int rr = quad * 4 + r;
            int qq = q0 + wave * 16 + rr;
            if (qq < SEQ)
                o[(size_t)(b * SEQ + qq) * DMODEL + h * 64 + nf * 16 + l15] =
                    __float2bfloat16(oacc[nf][r] * Linv[wave * 16 + rr]);
        }
    }
}

// ---------------- small kernels -------------------------------------------------
__global__ __launch_bounds__(256) void cvt_bf16_k(const float* __restrict__ s,
                                                  __hip_bfloat16* __restrict__ d, int n) {
    int i = blockIdx.x * 256 + threadIdx.x;
    if (i < n) d[i] = __float2bfloat16(s[i]);
}

// fused: splice mask tokens + restore + pos embed + LN1
__global__ __launch_bounds__(256) void asm_ln1(const float* __restrict__ x1,
        const int* __restrict__ ids, const float* __restrict__ mask_tok,
        const float* __restrict__ pos, const float* __restrict__ g,
        const float* __restrict__ bt, float* __restrict__ xres,
        __hip_bfloat16* __restrict__ y) {
    int row = blockIdx.x;
    int t = threadIdx.x;
    __shared__ float sbuf[256];
    int b = row / SEQ, p = row - b * SEQ;
    const float* srcrow;
    if (p == 0) {
        srcrow = x1 + (size_t)(b * 65) * DMODEL;
    } else {
        int i = ids[b * 256 + p - 1];
        srcrow = (i < 64) ? (x1 + (size_t)(b * 65 + 1 + i) * DMODEL) : mask_tok;
    }
    const float* posr = pos + (size_t)p * DMODEL;
    float a0 = srcrow[t] + posr[t];
    float a1 = srcrow[t + 256] + posr[t + 256];
    float* xr = xres + (size_t)row * DMODEL;
    xr[t] = a0;
    xr[t + 256] = a1;
    sbuf[t] = a0 + a1;
    __syncthreads();
    for (int s = 128; s > 0; s >>= 1) { if (t < s) sbuf[t] += sbuf[t + s]; __syncthreads(); }
    float mean = sbuf[0] * (1.0f / DMODEL);
    __syncthreads();
    float d0 = a0 - mean, d1 = a1 - mean;
    sbuf[t] = d0 * d0 + d1 * d1;
    __syncthreads();
    for (int s = 128; s > 0; s >>= 1) { if (t < s) sbuf[t] += sbuf[t + s]; __syncthreads(); }
    float inv = rsqrtf(sbuf[0] * (1.0f / DMODEL) + 1e-5f);
    __hip_bfloat16* yr = y + (size_t)row * DMODEL;
    yr[t]       = __float2bfloat16(d0 * inv * g[t]       + bt[t]);
    yr[t + 256] = __float2bfloat16(d1 * inv * g[t + 256] + bt[t + 256]);
}

// W9 plane layout: W9[o*4608 + plane*512 + f], plane 0 = base, 1+q = spline*scaler
__global__ __launch_bounds__(256) void buildw9p(const float* base, const float* spline,
                                                const float* scaler, ushortT* W9, int total) {
    int gid = blockIdx.x * 256 + threadIdx.x;
    if (gid >= total) return;
    int f = gid & 511;
    int o = gid >> 9;
    size_t w = (size_t)o * 4608;
    W9[w + f] = f2bf(base[gid]);
    float sc = scaler[gid];
#pragma unroll
    for (int q = 0; q < 8; ++q)
        W9[w + (size_t)(1 + q) * 512 + f] = f2bf(spline[(size_t)gid * 8 + q] * sc);
}

// E9 plane layout: E9[r*4608 + plane*512 + f]; one wave owns one row.
// DOLN=1: apply LayerNorm (g,bt) to the row before silu/spline expansion.
template<int DOLN>
__global__ __launch_bounds__(256) void expand9p(const float* __restrict__ src,
        const float* __restrict__ g, const float* __restrict__ bt,
        ushortT* __restrict__ E9, int row0, int nrows) {
    const int w = threadIdx.x >> 6;
    const int lane = threadIdx.x & 63;
    const int r = blockIdx.x * 4 + w;
    if (r >= nrows) return;
    const float* xr = src + (size_t)(row0 + r) * DMODEL + lane * 8;
    float v[8];
    *(float4*)&v[0] = *(const float4*)&xr[0];
    *(float4*)&v[4] = *(const float4*)&xr[4];
    if (DOLN) {
        float s = 0.f;
#pragma unroll
        for (int j = 0; j < 8; ++j) s += v[j];
#pragma unroll
        for (int off = 1; off < 64; off <<= 1) s += __shfl_xor(s, off, 64);
        float mean = s * (1.0f / DMODEL);
        float vs = 0.f;
#pragma unroll
        for (int j = 0; j < 8; ++j) { v[j] -= mean; vs += v[j] * v[j]; }
#pragma unroll
        for (int off = 1; off < 64; off <<= 1) vs += __shfl_xor(vs, off, 64);
        float inv = rsqrtf(vs * (1.0f / DMODEL) + 1e-5f);
        float gw[8], bw[8];
        *(float4*)&gw[0] = *(const float4*)&g[lane * 8];
        *(float4*)&gw[4] = *(const float4*)&g[lane * 8 + 4];
        *(float4*)&bw[0] = *(const float4*)&bt[lane * 8];
        *(float4*)&bw[4] = *(const float4*)&bt[lane * 8 + 4];
#pragma unroll
        for (int j = 0; j < 8; ++j) v[j] = v[j] * inv * gw[j] + bw[j];
    }
    ushortT pl[9][8];
#pragma unroll
    for (int j = 0; j < 8; ++j) {
        float x = v[j];
        pl[0][j] = f2bf(x / (1.0f + __expf(-x)));
        float bas[8];
        bspline8(x, bas);
#pragma unroll
        for (int q = 0; q < 8; ++q) pl[1 + q][j] = f2bf(bas[q]);
    }
    ushortT* e = E9 + (size_t)r * 4608 + lane * 8;
#pragma unroll
    for (int pp = 0; pp < 9; ++pp) *(int4*)&e[(size_t)pp * 512] = *(int4*)pl[pp];
}

__global__ void zero_k(float* p, int n) {
    int i = blockIdx.x * 256 + threadIdx.x;
    if (i < n) p[i] = 0.0f;
}
__global__ void fill_out_k(float* o, int n) {
    int i = blockIdx.x * 256 + threadIdx.x;
    if (i < n) o[i] = 333.0f;
}
__global__ void diag_host_k(float* o, float val) {
    if (threadIdx.x == 0 && blockIdx.x == 0) o[0] = val;
}

// ---------------- launcher ---------------------------------------------------
extern "C" void kernel_launch(void* const* d_in, const int* in_sizes, int n_in,
                              void* d_out, int out_size, void* d_ws, size_t ws_size,
                              hipStream_t stream) {
    const float* x      = (const float*)d_in[0];
    const int*   ids    = (const int*)d_in[1];
    const float* dec_w  = (const float*)d_in[2];
    const float* dec_b  = (const float*)d_in[3];
    const float* mask_t = (const float*)d_in[4];
    const float* pos    = (const float*)d_in[5];
    const float* ln1_g  = (const float*)d_in[6];
    const float* ln1_b  = (const float*)d_in[7];
    const float* in_w   = (const float*)d_in[8];
    const float* in_b   = (const float*)d_in[9];
    const float* out_w  = (const float*)d_in[10];
    const float* out_b  = (const float*)d_in[11];
    const float* ln2_g  = (const float*)d_in[12];
    const float* ln2_b  = (const float*)d_in[13];
    const float* k1_base = (const float*)d_in[14];
    const float* k1_spl  = (const float*)d_in[15];
    const float* k1_sc   = (const float*)d_in[16];
    const float* k2_base = (const float*)d_in[17];
    const float* k2_spl  = (const float*)d_in[18];
    const float* k2_sc   = (const float*)d_in[19];
    float* out = (float*)d_out;

    static const int exp_sizes[20] = {
        1597440, 16384, 196608, 512, 512, 524800, 512, 512,
        786432, 1536, 262144, 512, 512, 512,
        262144, 2097152, 262144, 131072, 1048576, 131072
    };
    int bad = -1;
    if (n_in != 20) bad = 55;
    else {
        for (int i = 0; i < 20; ++i)
            if (in_sizes[i] != exp_sizes[i]) { bad = i; break; }
        if (bad < 0 && out_size != 4194304) bad = 56;
    }
    if (bad >= 0) {
        fill_out_k<<<(out_size + 255) / 256, 256, 0, stream>>>(out, out_size);
        diag_host_k<<<1, 64, 0, stream>>>(out, ldexpf(1.0f, 30 + bad));
        return;
    }

    // ---- workspace layout (float offsets; peak concurrent fits 44,368,384) ----
    // W9a/W9b/zeros: persistent [0, 1769984)
    // xres  [1769984, 10224128)        alive: asm_ln1 -> KAN1 expand c2
    // hbufb [10224128, 14451200)       alive: asm_ln1 -> outproj
    // qkvb  [14451200, 27132416)       alive: QKV -> attn   (x1/xbf inside, earlier)
    // kan1o [10224128, 18645504)       alive: after outproj (over dead hbufb+qkvb head)
    // E9    [18645504, 37593600)       alive: KAN phases (over dead qkvb tail)
    // dec/in/out weights bf16 [37593600, 38216192)
    float* ws = (float*)d_ws;
    ushortT* W9a   = (ushortT*)(ws);                    // 512*4608 bf16
    ushortT* W9b   = (ushortT*)(ws + 1179648);          // 256*4608 bf16
    float*   zeros = ws + 1769472;                      // 512 f32
    float*   xres  = ws + 1769984;                      // 16512*512 f32
    __hip_bfloat16* hbufb = (__hip_bfloat16*)(ws + 10224128);  // 16512*512 bf16
    ushortT* qkvb  = (ushortT*)(ws + 14451200);         // 16512*1536 bf16
    float*   x1    = ws + 14451200;                     // 4224*512 f32
    ushortT* xbf   = (ushortT*)(ws + 16613888);         // 4224*384 bf16
    float*   kan1o = ws + 10224128;                     // 16448*512 f32
    ushortT* E9    = (ushortT*)(ws + 18645504);         // 8224*4608 bf16
    ushortT* dec_wb = (ushortT*)(ws + 37593600);
    ushortT* in_wb  = (ushortT*)(ws + 37691904);
    ushortT* out_wb = (ushortT*)(ws + 38085120);

    // 0. one-time converts + zeros
    zero_k<<<2, 256, 0, stream>>>(zeros, 512);
    cvt_bf16_k<<<(1597440 + 255) / 256, 256, 0, stream>>>(x, (__hip_bfloat16*)xbf, 1597440);
    cvt_bf16_k<<<(196608 + 255) / 256, 256, 0, stream>>>(dec_w, (__hip_bfloat16*)dec_wb, 196608);
    cvt_bf16_k<<<(786432 + 255) / 256, 256, 0, stream>>>(in_w, (__hip_bfloat16*)in_wb, 786432);
    cvt_bf16_k<<<(262144 + 255) / 256, 256, 0, stream>>>(out_w, (__hip_bfloat16*)out_wb, 262144);
    buildw9p<<<(262144 + 255) / 256, 256, 0, stream>>>(k1_base, k1_spl, k1_sc, W9a, 262144);
    buildw9p<<<(131072 + 255) / 256, 256, 0, stream>>>(k2_base, k2_spl, k2_sc, W9b, 131072);

    // 1. decoder embed projection -> x1 f32
    gemm_t<0><<<dim3(4, 33), 256, 0, stream>>>(xbf, dec_wb, dec_b, nullptr, x1,
                                               512, 384, 4224, 0, 384);
    // 2+3. fused splice + gather + pos + LN1 -> xres f32, hbufb bf16
    asm_ln1<<<ROWS, 256, 0, stream>>>(x1, ids, mask_t, pos, ln1_g, ln1_b, xres, hbufb);
    // 4. QKV -> qkvb bf16 (x1/xbf dead)
    gemm_t<1><<<dim3(12, 129), 256, 0, stream>>>((const ushortT*)hbufb, in_wb, in_b, nullptr,
                                                 qkvb, 1536, 512, 16512, 0, 512);
    // 5. attention -> hbufb bf16
    attn_mf2<<<dim3(5, BATCH * 8), 256, 0, stream>>>(qkvb, hbufb);
    // 6. out-proj + residual -> xres f32 (LN2 fused into expand)
    gemm_t<0><<<dim3(4, 129), 256, 0, stream>>>((const ushortT*)hbufb, out_wb, out_b, xres,
                                                xres, 512, 512, 16512, 0, 512);

    // zero-init split-K accumulators (hbufb/qkvb dead now)
    zero_k<<<(ROWS * 512 + 255) / 256, 256, 0, stream>>>(kan1o, ROWS * 512);
    zero_k<<<(4194304 + 255) / 256, 256, 0, stream>>>(out, 4194304);

    // 7+8. KAN1: 2 chunks of 8224; expand fuses LN2; gemm split-K=4 atomics -> kan1o
    // (z=4 -> 1040 blocks ~ 4.06/CU; R6 profile showed z=2's 520 blocks = Occ 17%)
    for (int c = 0; c < 2; ++c) {
        int r0 = c * HCHUNK;
        expand9p<1><<<(HCHUNK + 3) / 4, 256, 0, stream>>>(xres, ln2_g, ln2_b, E9, r0, HCHUNK);
        gemm_t<3><<<dim3(4, 65, 4), 256, 0, stream>>>(E9, W9a, zeros, nullptr,
                                                      kan1o + (size_t)r0 * 512,
                                                      512, 4608, HCHUNK, 0, 1152);
    }
    // 9. KAN2: 2 chunks; gemm split-K=8 atomics -> out (p==0 drop fused)
    for (int c = 0; c < 2; ++c) {
        int r0 = c * HCHUNK;
        expand9p<0><<<(HCHUNK + 3) / 4, 256, 0, stream>>>(kan1o, ln2_g, ln2_b, E9, r0, HCHUNK);
        gemm_t<4><<<dim3(2, 65, 8), 256, 0, stream>>>(E9, W9b, zeros, nullptr,
                                                      out, 256, 4608, HCHUNK, r0, 576);
    }
    (void)ws_size;
}

// Round 16
// 740.005 us; speedup vs baseline: 1.1187x; 1.1187x over previous
//
#include <hip/hip_runtime.h>
#include <hip/hip_bf16.h>
#include <math.h>

#define DMODEL 512
#define SEQ    257
#define BATCH  64
#define ROWS   (BATCH * SEQ)   // 16448
#define ROWSP  16512
#define HCHUNK 8224            // ROWS/2, per-chunk rows for KAN

typedef unsigned short ushortT;
typedef __attribute__((ext_vector_type(8))) __bf16 bf16x8;
typedef __attribute__((ext_vector_type(4))) float f32x4;

__device__ __forceinline__ ushortT f2bf(float v) {
    __hip_bfloat16 t = __float2bfloat16(v);
    return *(ushortT*)&t;
}
__device__ __forceinline__ float bf2f(ushortT u) {
    return __bfloat162float(*(__hip_bfloat16*)&u);
}

// async 16B global->LDS (wave-uniform LDS base + lane*16)
__device__ __forceinline__ void gl16(const ushortT* g, ushortT* l) {
    __builtin_amdgcn_global_load_lds(
        (const __attribute__((address_space(1))) void*)g,
        (__attribute__((address_space(3))) void*)l, 16, 0, 0);
}

// ---------------- cubic B-spline bases (closed form, uniform grid) -------------
__device__ __forceinline__ void bspline8(float x, float bas[8]) {
    const float k6 = 1.0f / 6.0f;
    float t = (x + 2.2f) * 2.5f;
    float fm = floorf(t);
    int m = (int)fm;
    float u = t - fm;
    float u2 = u * u, u3 = u2 * u;
    float omu = 1.0f - u;
    float p0 = u3 * k6;
    float p1 = (-3.0f * u3 + 3.0f * u2 + 3.0f * u + 1.0f) * k6;
    float p2 = (3.0f * u3 - 6.0f * u2 + 4.0f) * k6;
    float p3 = omu * omu * omu * k6;
#pragma unroll
    for (int q = 0; q < 8; ++q) {
        int d = m - q;
        float v = (d == 0) ? p0 : (d == 1) ? p1 : (d == 2) ? p2 : (d == 3) ? p3 : 0.0f;
        bas[q] = v;
    }
}

// ---------------- bf16 MFMA GEMM (pipelined global_load_lds, split-K capable) --
// C[M,N] = A[M,K] @ B[N,K]^T. Tiles 128x128, 4 waves. blockIdx.z = K-split slice.
// K-loop software-pipelined: LDS double-buffer, stage tile t+1 BEFORE compute of
// tile t. R10 lesson: the RAW fence (prefetch writes -> next iter's ds_reads)
// must be an EXPLICIT vmcnt(0) before the barrier — the compiler does not
// reliably emit it in this shape (intermittent post-timing divergence, absmax
// 4.18). Drain placed after the MFMAs so load latency still hides under compute.
// MODE 0: f32 store + bias (+R residual). MODE 1: bf16 store + bias.
// MODE 3: f32 atomicAdd, no bias (KAN1 partials). MODE 4: atomicAdd into out with
//         (b,p-1) remap, p==0 dropped, no bias (KAN2).
template<int MODE>
__global__ __launch_bounds__(256) void gemm_t(
    const ushortT* __restrict__ A, const ushortT* __restrict__ B,
    const float* __restrict__ bias, const float* __restrict__ R,
    void* __restrict__ Cv, int N, int K, int Mreal, int rowoff, int Ks) {
    __shared__ __align__(16) ushortT As[2][128 * 32];
    __shared__ __align__(16) ushortT Bs[2][128 * 32];
    const int tid = threadIdx.x;
    const int wave = tid >> 6, lane = tid & 63;
    // bijective XCD swizzle (8 XCDs) over the (x,y) plane
    const int nwg = gridDim.x * gridDim.y;
    const int lin = blockIdx.y * gridDim.x + blockIdx.x;
    const int xcd = lin & 7, sidx = lin >> 3;
    const int qn = nwg >> 3, rn = nwg & 7;
    const int nlin = (xcd < rn ? xcd * (qn + 1) : rn * (qn + 1) + (xcd - rn) * qn) + sidx;
    const int bm = (nlin / gridDim.x) * 128, bn = (nlin % gridDim.x) * 128;
    const int wm = (wave >> 1) * 64, wn = (wave & 1) * 64;
    const int srow = tid >> 2;
    const int scol = (tid & 3) * 8;
    const int mrow = lane & 15;
    const int kq = (lane >> 4) * 8;
    f32x4 acc[4][4];
#pragma unroll
    for (int i = 0; i < 4; ++i)
#pragma unroll
        for (int j = 0; j < 4; ++j) acc[i][j] = (f32x4){0.f, 0.f, 0.f, 0.f};

    // row-clamped A staging (allows Mreal not multiple of 128)
    int ar0 = bm + srow;      if (ar0 > Mreal - 1) ar0 = Mreal - 1;
    int ar1 = bm + srow + 64; if (ar1 > Mreal - 1) ar1 = Mreal - 1;
    const ushortT* Ab0 = A + (size_t)ar0 * K + scol;
    const ushortT* Ab1 = A + (size_t)ar1 * K + scol;
    const ushortT* Bb  = B + (size_t)(bn + srow) * K + scol;
    const int kb = blockIdx.z * Ks;
    const int ke = kb + Ks;

    // prologue: stage first tile into buf 0
    {
        ushortT* a = As[0] + wave * 512;
        ushortT* b = Bs[0] + wave * 512;
        gl16(Ab0 + kb, a);
        gl16(Ab1 + kb, a + 2048);
        gl16(Bb + kb, b);
        gl16(Bb + kb + (size_t)64 * K, b + 2048);
    }
    asm volatile("s_waitcnt vmcnt(0)" ::: "memory");
    __builtin_amdgcn_sched_barrier(0);
    __syncthreads();   // tile 0 resident for ALL waves
    int cur = 0;
    for (int k0 = kb; k0 < ke; k0 += 32) {
        const int kn = k0 + 32;
        if (kn < ke) {   // issue next tile's loads BEFORE compute (overlap)
            ushortT* a = As[cur ^ 1] + wave * 512;
            ushortT* b = Bs[cur ^ 1] + wave * 512;
            gl16(Ab0 + kn, a);
            gl16(Ab1 + kn, a + 2048);
            gl16(Bb + kn, b);
            gl16(Bb + kn + (size_t)64 * K, b + 2048);
        }
        bf16x8 af[4], bfr[4];
#pragma unroll
        for (int i = 0; i < 4; ++i)
            af[i] = *(const bf16x8*)&As[cur][(wm + i * 16 + mrow) * 32 + kq];
#pragma unroll
        for (int j = 0; j < 4; ++j)
            bfr[j] = *(const bf16x8*)&Bs[cur][(wn + j * 16 + mrow) * 32 + kq];
#pragma unroll
        for (int i = 0; i < 4; ++i)
#pragma unroll
            for (int j = 0; j < 4; ++j)
                acc[i][j] = __builtin_amdgcn_mfma_f32_16x16x32_bf16(af[i], bfr[j], acc[i][j], 0, 0, 0);
        // explicit RAW fence: prefetched gl16 writes must land before any wave
        // reads buf[cur^1] next iter. Placed AFTER the MFMAs so load latency
        // overlaps compute.
        asm volatile("s_waitcnt vmcnt(0)" ::: "memory");
        __builtin_amdgcn_sched_barrier(0);
        __syncthreads();
        cur ^= 1;
    }
    const int r0q = (lane >> 4) * 4;
    const int cn = lane & 15;
#pragma unroll
    for (int i = 0; i < 4; ++i) {
#pragma unroll
        for (int j = 0; j < 4; ++j) {
            int col = bn + wn + j * 16 + cn;
            float bv = (MODE <= 1) ? bias[col] : 0.0f;
#pragma unroll
            for (int r = 0; r < 4; ++r) {
                int row = bm + wm + i * 16 + r0q + r;
                float v = acc[i][j][r] + bv;
                if (MODE == 1) {
                    if (row < Mreal)
                        ((__hip_bfloat16*)Cv)[(size_t)row * N + col] = __float2bfloat16(v);
                } else if (MODE == 0) {
                    if (row < Mreal) {
                        size_t idx = (size_t)row * N + col;
                        if (R) v += R[idx];
                        ((float*)Cv)[idx] = v;
                    }
                } else if (MODE == 3) {
                    if (row < Mreal)
                        atomicAdd(&((float*)Cv)[(size_t)row * N + col], v);
                } else {  // MODE 4
                    if (row < Mreal) {
                        int grow = rowoff + row;
                        int bb = grow / SEQ;
                        int pp = grow - bb * SEQ;
                        if (pp > 0)
                            atomicAdd(&((float*)Cv)[((size_t)(bb * 256 + pp - 1)) * 256 + col], v);
                    }
                }
            }
        }
    }
}

// ---------------- attention v3: 4 waves / 64 q-rows, padded LDS strides --------
// grid (5 qtiles, 512 bh); block 256 (4 waves). LDS 80128 B -> 2 blocks/CU.
// K view [272][72] (stride 144B, 2-way); Vt [64][328]+XOR (2-way); Sc stride 296.
__global__ __launch_bounds__(256) void attn_mf2(const ushortT* __restrict__ qkvb,
                                                __hip_bfloat16* __restrict__ o) {
    __shared__ __align__(16) ushortT KV[20992];  // max(272*72, 64*328)
    __shared__ __align__(16) ushortT Sc[64 * 296];
    __shared__ float Linv[64];
    const int tid = threadIdx.x;
    const int wave = tid >> 6, lane = tid & 63;
    const int l15 = lane & 15;
    const int quad = lane >> 4;
    // XCD-chunked swizzle: nwg = 2560 (div by 8); 5 qtiles of one bh share an XCD L2
    const int lin = blockIdx.y * gridDim.x + blockIdx.x;
    const int w = (lin & 7) * 320 + (lin >> 3);
    const int q0 = (w % 5) * 64;
    const int bh = w / 5;
    const int h = bh & 7, b = bh >> 3;
    const size_t base = (size_t)(b * SEQ) * 1536;

    // stage K [272][72] (rows >= SEQ zero)
    for (int g = tid; g < 272 * 8; g += 256) {
        int k = g >> 3;
        int d0 = (g & 7) * 8;
        int4 v;
        if (k < SEQ) v = *(const int4*)&qkvb[base + (size_t)k * 1536 + 512 + h * 64 + d0];
        else v = (int4){0, 0, 0, 0};
        *(int4*)&KV[k * 72 + d0] = v;
    }
    // Q fragments, exact *0.125 (power of 2)
    int q = q0 + wave * 16 + l15;
    if (q > SEQ - 1) q = SEQ - 1;
    bf16x8 qf[2];
#pragma unroll
    for (int c = 0; c < 2; ++c) {
        union { bf16x8 v8; ushortT u[8]; } r;
        r.v8 = *(const bf16x8*)&qkvb[base + (size_t)q * 1536 + h * 64 + quad * 8 + c * 32];
#pragma unroll
        for (int i = 0; i < 8; ++i)
            r.u[i] = f2bf(bf2f(r.u[i]) * 0.125f);
        qf[c] = r.v8;
    }
    __syncthreads();

    // S = (Q/8) K^T -> Sc bf16 (cols 0..271)
    __builtin_amdgcn_s_setprio(1);
    for (int kt = 0; kt < 17; ++kt) {
        f32x4 sacc = (f32x4){0.f, 0.f, 0.f, 0.f};
#pragma unroll
        for (int c = 0; c < 2; ++c) {
            bf16x8 kf = *(const bf16x8*)&KV[(kt * 16 + l15) * 72 + c * 32 + quad * 8];
            sacc = __builtin_amdgcn_mfma_f32_16x16x32_bf16(qf[c], kf, sacc, 0, 0, 0);
        }
#pragma unroll
        for (int r = 0; r < 4; ++r)
            Sc[(wave * 16 + quad * 4 + r) * 296 + kt * 16 + l15] = f2bf(sacc[r]);
    }
    __builtin_amdgcn_s_setprio(0);
    __syncthreads();   // all S reads of K done; Sc fully written

    // stage Vt [64][328] with XOR swizzle: addr(d,key) = d*328 + (key ^ ((d>>3)*8))
    for (int g = tid; g < 288 * 8; g += 256) {
        int key = g >> 3;
        int d0 = (g & 7) * 8;           // swizzle mask for d in [d0,d0+8)
        ushortT tmp[8];
        if (key < SEQ) {
            int4 v = *(const int4*)&qkvb[base + (size_t)key * 1536 + 1024 + h * 64 + d0];
            *(int4*)tmp = v;
        } else {
#pragma unroll
            for (int i = 0; i < 8; ++i) tmp[i] = 0;
        }
        int sk = key ^ d0;
#pragma unroll
        for (int i = 0; i < 8; ++i) KV[(d0 + i) * 328 + sk] = tmp[i];
    }
    // softmax: 4 threads/row, vectorized bf16x8; pad cols [SEQ,288) = -1e30 first
    {
        int row = tid >> 2;             // 0..63
        int stripe = tid & 3;
        ushortT* sr = &Sc[row * 296];
        ushortT NEG = f2bf(-1e30f);
        for (int c = SEQ + stripe; c < 288; c += 4) sr[c] = NEG;
        float m = -1e30f;
#pragma unroll
        for (int it = 0; it < 9; ++it) {
            union { bf16x8 v8; ushortT u[8]; } rr;
            rr.v8 = *(const bf16x8*)&sr[stripe * 8 + it * 32];
#pragma unroll
            for (int j = 0; j < 8; ++j) m = fmaxf(m, bf2f(rr.u[j]));
        }
        m = fmaxf(m, __shfl_xor(m, 1, 64));
        m = fmaxf(m, __shfl_xor(m, 2, 64));
        float l = 0.f;
#pragma unroll
        for (int it = 0; it < 9; ++it) {
            union { bf16x8 v8; ushortT u[8]; } rr;
            ushortT* p = &sr[stripe * 8 + it * 32];
            rr.v8 = *(const bf16x8*)p;
#pragma unroll
            for (int j = 0; j < 8; ++j) {
                float e = __expf(bf2f(rr.u[j]) - m);
                l += e;
                rr.u[j] = f2bf(e);
            }
            *(bf16x8*)p = rr.v8;
        }
        l += __shfl_xor(l, 1, 64);
        l += __shfl_xor(l, 2, 64);
        if (stripe == 0) Linv[row] = 1.0f / l;
    }
    __syncthreads();

    // O = P V
    f32x4 oacc[4];
#pragma unroll
    for (int nf = 0; nf < 4; ++nf) oacc[nf] = (f32x4){0.f, 0.f, 0.f, 0.f};
    __builtin_amdgcn_s_setprio(1);
    for (int kc = 0; kc < 9; ++kc) {
        bf16x8 pf = *(const bf16x8*)&Sc[(wave * 16 + l15) * 296 + kc * 32 + quad * 8];
#pragma unroll
        for (int nf = 0; nf < 4; ++nf) {
            int d = nf * 16 + l15;
            int mask = ((d >> 3) & 7) * 8;
            bf16x8 vf = *(const bf16x8*)&KV[d * 328 + ((kc * 32 + quad * 8) ^ mask)];
            oacc[nf] = __builtin_amdgcn_mfma_f32_16x16x32_bf16(pf, vf, oacc[nf], 0, 0, 0);
        }
    }
    __builtin_amdgcn_s_setprio(0);
#pragma unroll
    for (int nf = 0; nf < 4; ++nf) {
#pragma unroll
        for (int r = 0; r < 4; ++r) {
            int rr = quad * 4 + r;
            int qq = q0 + wave * 16 + rr;
            if (qq < SEQ)
                o[(size_t)(b * SEQ + qq) * DMODEL + h * 64 + nf * 16 + l15] =
                    __float2bfloat16(oacc[nf][r] * Linv[wave * 16 + rr]);
        }
    }
}

// ---------------- small kernels -------------------------------------------------
__global__ __launch_bounds__(256) void cvt_bf16_k(const float* __restrict__ s,
                                                  __hip_bfloat16* __restrict__ d, int n) {
    int i = blockIdx.x * 256 + threadIdx.x;
    if (i < n) d[i] = __float2bfloat16(s[i]);
}

// fused: splice mask tokens + restore + pos embed + LN1
__global__ __launch_bounds__(256) void asm_ln1(const float* __restrict__ x1,
        const int* __restrict__ ids, const float* __restrict__ mask_tok,
        const float* __restrict__ pos, const float* __restrict__ g,
        const float* __restrict__ bt, float* __restrict__ xres,
        __hip_bfloat16* __restrict__ y) {
    int row = blockIdx.x;
    int t = threadIdx.x;
    __shared__ float sbuf[256];
    int b = row / SEQ, p = row - b * SEQ;
    const float* srcrow;
    if (p == 0) {
        srcrow = x1 + (size_t)(b * 65) * DMODEL;
    } else {
        int i = ids[b * 256 + p - 1];
        srcrow = (i < 64) ? (x1 + (size_t)(b * 65 + 1 + i) * DMODEL) : mask_tok;
    }
    const float* posr = pos + (size_t)p * DMODEL;
    float a0 = srcrow[t] + posr[t];
    float a1 = srcrow[t + 256] + posr[t + 256];
    float* xr = xres + (size_t)row * DMODEL;
    xr[t] = a0;
    xr[t + 256] = a1;
    sbuf[t] = a0 + a1;
    __syncthreads();
    for (int s = 128; s > 0; s >>= 1) { if (t < s) sbuf[t] += sbuf[t + s]; __syncthreads(); }
    float mean = sbuf[0] * (1.0f / DMODEL);
    __syncthreads();
    float d0 = a0 - mean, d1 = a1 - mean;
    sbuf[t] = d0 * d0 + d1 * d1;
    __syncthreads();
    for (int s = 128; s > 0; s >>= 1) { if (t < s) sbuf[t] += sbuf[t + s]; __syncthreads(); }
    float inv = rsqrtf(sbuf[0] * (1.0f / DMODEL) + 1e-5f);
    __hip_bfloat16* yr = y + (size_t)row * DMODEL;
    yr[t]       = __float2bfloat16(d0 * inv * g[t]       + bt[t]);
    yr[t + 256] = __float2bfloat16(d1 * inv * g[t + 256] + bt[t + 256]);
}

// W9 plane layout: W9[o*4608 + plane*512 + f], plane 0 = base, 1+q = spline*scaler
__global__ __launch_bounds__(256) void buildw9p(const float* base, const float* spline,
                                                const float* scaler, ushortT* W9, int total) {
    int gid = blockIdx.x * 256 + threadIdx.x;
    if (gid >= total) return;
    int f = gid & 511;
    int o = gid >> 9;
    size_t w = (size_t)o * 4608;
    W9[w + f] = f2bf(base[gid]);
    float sc = scaler[gid];
#pragma unroll
    for (int q = 0; q < 8; ++q)
        W9[w + (size_t)(1 + q) * 512 + f] = f2bf(spline[(size_t)gid * 8 + q] * sc);
}

// E9 plane layout: E9[r*4608 + plane*512 + f]; one wave owns one row.
// DOLN=1: apply LayerNorm (g,bt) to the row before silu/spline expansion.
template<int DOLN>
__global__ __launch_bounds__(256) void expand9p(const float* __restrict__ src,
        const float* __restrict__ g, const float* __restrict__ bt,
        ushortT* __restrict__ E9, int row0, int nrows) {
    const int w = threadIdx.x >> 6;
    const int lane = threadIdx.x & 63;
    const int r = blockIdx.x * 4 + w;
    if (r >= nrows) return;
    const float* xr = src + (size_t)(row0 + r) * DMODEL + lane * 8;
    float v[8];
    *(float4*)&v[0] = *(const float4*)&xr[0];
    *(float4*)&v[4] = *(const float4*)&xr[4];
    if (DOLN) {
        float s = 0.f;
#pragma unroll
        for (int j = 0; j < 8; ++j) s += v[j];
#pragma unroll
        for (int off = 1; off < 64; off <<= 1) s += __shfl_xor(s, off, 64);
        float mean = s * (1.0f / DMODEL);
        float vs = 0.f;
#pragma unroll
        for (int j = 0; j < 8; ++j) { v[j] -= mean; vs += v[j] * v[j]; }
#pragma unroll
        for (int off = 1; off < 64; off <<= 1) vs += __shfl_xor(vs, off, 64);
        float inv = rsqrtf(vs * (1.0f / DMODEL) + 1e-5f);
        float gw[8], bw[8];
        *(float4*)&gw[0] = *(const float4*)&g[lane * 8];
        *(float4*)&gw[4] = *(const float4*)&g[lane * 8 + 4];
        *(float4*)&bw[0] = *(const float4*)&bt[lane * 8];
        *(float4*)&bw[4] = *(const float4*)&bt[lane * 8 + 4];
#pragma unroll
        for (int j = 0; j < 8; ++j) v[j] = v[j] * inv * gw[j] + bw[j];
    }
    ushortT pl[9][8];
#pragma unroll
    for (int j = 0; j < 8; ++j) {
        float x = v[j];
        pl[0][j] = f2bf(x / (1.0f + __expf(-x)));
        float bas[8];
        bspline8(x, bas);
#pragma unroll
        for (int q = 0; q < 8; ++q) pl[1 + q][j] = f2bf(bas[q]);
    }
    ushortT* e = E9 + (size_t)r * 4608 + lane * 8;
#pragma unroll
    for (int pp = 0; pp < 9; ++pp) *(int4*)&e[(size_t)pp * 512] = *(int4*)pl[pp];
}

__global__ void zero_k(float* p, int n) {
    int i = blockIdx.x * 256 + threadIdx.x;
    if (i < n) p[i] = 0.0f;
}
__global__ void fill_out_k(float* o, int n) {
    int i = blockIdx.x * 256 + threadIdx.x;
    if (i < n) o[i] = 333.0f;
}
__global__ void diag_host_k(float* o, float val) {
    if (threadIdx.x == 0 && blockIdx.x == 0) o[0] = val;
}

// ---------------- launcher ---------------------------------------------------
extern "C" void kernel_launch(void* const* d_in, const int* in_sizes, int n_in,
                              void* d_out, int out_size, void* d_ws, size_t ws_size,
                              hipStream_t stream) {
    const float* x      = (const float*)d_in[0];
    const int*   ids    = (const int*)d_in[1];
    const float* dec_w  = (const float*)d_in[2];
    const float* dec_b  = (const float*)d_in[3];
    const float* mask_t = (const float*)d_in[4];
    const float* pos    = (const float*)d_in[5];
    const float* ln1_g  = (const float*)d_in[6];
    const float* ln1_b  = (const float*)d_in[7];
    const float* in_w   = (const float*)d_in[8];
    const float* in_b   = (const float*)d_in[9];
    const float* out_w  = (const float*)d_in[10];
    const float* out_b  = (const float*)d_in[11];
    const float* ln2_g  = (const float*)d_in[12];
    const float* ln2_b  = (const float*)d_in[13];
    const float* k1_base = (const float*)d_in[14];
    const float* k1_spl  = (const float*)d_in[15];
    const float* k1_sc   = (const float*)d_in[16];
    const float* k2_base = (const float*)d_in[17];
    const float* k2_spl  = (const float*)d_in[18];
    const float* k2_sc   = (const float*)d_in[19];
    float* out = (float*)d_out;

    static const int exp_sizes[20] = {
        1597440, 16384, 196608, 512, 512, 524800, 512, 512,
        786432, 1536, 262144, 512, 512, 512,
        262144, 2097152, 262144, 131072, 1048576, 131072
    };
    int bad = -1;
    if (n_in != 20) bad = 55;
    else {
        for (int i = 0; i < 20; ++i)
            if (in_sizes[i] != exp_sizes[i]) { bad = i; break; }
        if (bad < 0 && out_size != 4194304) bad = 56;
    }
    if (bad >= 0) {
        fill_out_k<<<(out_size + 255) / 256, 256, 0, stream>>>(out, out_size);
        diag_host_k<<<1, 64, 0, stream>>>(out, ldexpf(1.0f, 30 + bad));
        return;
    }

    // ---- workspace layout (float offsets; peak concurrent fits 44,368,384) ----
    // W9a/W9b/zeros: persistent [0, 1769984)
    // xres  [1769984, 10224128)        alive: asm_ln1 -> KAN1 expand c2
    // hbufb [10224128, 14451200)       alive: asm_ln1 -> outproj
    // qkvb  [14451200, 27132416)       alive: QKV -> attn   (x1/xbf inside, earlier)
    // kan1o [10224128, 18645504)       alive: after outproj (over dead hbufb+qkvb head)
    // E9    [18645504, 37593600)       alive: KAN phases (over dead qkvb tail)
    // dec/in/out weights bf16 [37593600, 38216192)
    float* ws = (float*)d_ws;
    ushortT* W9a   = (ushortT*)(ws);                    // 512*4608 bf16
    ushortT* W9b   = (ushortT*)(ws + 1179648);          // 256*4608 bf16
    float*   zeros = ws + 1769472;                      // 512 f32
    float*   xres  = ws + 1769984;                      // 16512*512 f32
    __hip_bfloat16* hbufb = (__hip_bfloat16*)(ws + 10224128);  // 16512*512 bf16
    ushortT* qkvb  = (ushortT*)(ws + 14451200);         // 16512*1536 bf16
    float*   x1    = ws + 14451200;                     // 4224*512 f32
    ushortT* xbf   = (ushortT*)(ws + 16613888);         // 4224*384 bf16
    float*   kan1o = ws + 10224128;                     // 16448*512 f32
    ushortT* E9    = (ushortT*)(ws + 18645504);         // 8224*4608 bf16
    ushortT* dec_wb = (ushortT*)(ws + 37593600);
    ushortT* in_wb  = (ushortT*)(ws + 37691904);
    ushortT* out_wb = (ushortT*)(ws + 38085120);

    // 0. one-time converts + zeros
    zero_k<<<2, 256, 0, stream>>>(zeros, 512);
    cvt_bf16_k<<<(1597440 + 255) / 256, 256, 0, stream>>>(x, (__hip_bfloat16*)xbf, 1597440);
    cvt_bf16_k<<<(196608 + 255) / 256, 256, 0, stream>>>(dec_w, (__hip_bfloat16*)dec_wb, 196608);
    cvt_bf16_k<<<(786432 + 255) / 256, 256, 0, stream>>>(in_w, (__hip_bfloat16*)in_wb, 786432);
    cvt_bf16_k<<<(262144 + 255) / 256, 256, 0, stream>>>(out_w, (__hip_bfloat16*)out_wb, 262144);
    buildw9p<<<(262144 + 255) / 256, 256, 0, stream>>>(k1_base, k1_spl, k1_sc, W9a, 262144);
    buildw9p<<<(131072 + 255) / 256, 256, 0, stream>>>(k2_base, k2_spl, k2_sc, W9b, 131072);

    // 1. decoder embed projection -> x1 f32
    gemm_t<0><<<dim3(4, 33), 256, 0, stream>>>(xbf, dec_wb, dec_b, nullptr, x1,
                                               512, 384, 4224, 0, 384);
    // 2+3. fused splice + gather + pos + LN1 -> xres f32, hbufb bf16
    asm_ln1<<<ROWS, 256, 0, stream>>>(x1, ids, mask_t, pos, ln1_g, ln1_b, xres, hbufb);
    // 4. QKV -> qkvb bf16 (x1/xbf dead)
    gemm_t<1><<<dim3(12, 129), 256, 0, stream>>>((const ushortT*)hbufb, in_wb, in_b, nullptr,
                                                 qkvb, 1536, 512, 16512, 0, 512);
    // 5. attention -> hbufb bf16
    attn_mf2<<<dim3(5, BATCH * 8), 256, 0, stream>>>(qkvb, hbufb);
    // 6. out-proj + residual -> xres f32 (LN2 fused into expand)
    gemm_t<0><<<dim3(4, 129), 256, 0, stream>>>((const ushortT*)hbufb, out_wb, out_b, xres,
                                                xres, 512, 512, 16512, 0, 512);

    // zero-init split-K accumulators (hbufb/qkvb dead now)
    zero_k<<<(ROWS * 512 + 255) / 256, 256, 0, stream>>>(kan1o, ROWS * 512);
    zero_k<<<(4194304 + 255) / 256, 256, 0, stream>>>(out, 4194304);

    // 7+8. KAN1: 2 chunks of 8224; expand fuses LN2; gemm split-K=2 atomics -> kan1o
    for (int c = 0; c < 2; ++c) {
        int r0 = c * HCHUNK;
        expand9p<1><<<(HCHUNK + 3) / 4, 256, 0, stream>>>(xres, ln2_g, ln2_b, E9, r0, HCHUNK);
        gemm_t<3><<<dim3(4, 65, 2), 256, 0, stream>>>(E9, W9a, zeros, nullptr,
                                                      kan1o + (size_t)r0 * 512,
                                                      512, 4608, HCHUNK, 0, 2304);
    }
    // 9. KAN2: 2 chunks; gemm split-K=4 atomics -> out (p==0 drop fused)
    for (int c = 0; c < 2; ++c) {
        int r0 = c * HCHUNK;
        expand9p<0><<<(HCHUNK + 3) / 4, 256, 0, stream>>>(kan1o, ln2_g, ln2_b, E9, r0, HCHUNK);
        gemm_t<4><<<dim3(2, 65, 4), 256, 0, stream>>>(E9, W9b, zeros, nullptr,
                                                      out, 256, 4608, HCHUNK, r0, 1152);
    }
    (void)ws_size;
}